// Round 7
// baseline (261.730 us; speedup 1.0000x reference)
//
#include <hip/hip_runtime.h>

typedef float  f32x4  __attribute__((ext_vector_type(4)));
typedef short  bf16x8 __attribute__((ext_vector_type(8)));

#define LOG2E    1.4426950408889634f
#define TWOLOG2E 2.8853900817779268f

__device__ __forceinline__ unsigned short f2b(float f) {      // fp32 -> bf16 RNE
    unsigned int u = __builtin_bit_cast(unsigned int, f);
    u += 0x7fffu + ((u >> 16) & 1u);
    return (unsigned short)(u >> 16);
}
__device__ __forceinline__ float b2f(unsigned short s) {
    unsigned int u = ((unsigned int)s) << 16;
    return __builtin_bit_cast(float, u);
}
__device__ __forceinline__ unsigned int pk2(float lo, float hi) { // 2xbf16 pack
    return (unsigned int)f2b(lo) | ((unsigned int)f2b(hi) << 16);
}
// sigmoid with input pre-scaled by log2e (folded into weights/bias)
__device__ __forceinline__ float sig2(float xh) {
    return __builtin_amdgcn_rcpf(1.0f + __builtin_amdgcn_exp2f(-xh));
}
// tanh with input pre-scaled by 2*log2e
__device__ __forceinline__ float th2(float xh) {
    return 2.0f * __builtin_amdgcn_rcpf(1.0f + __builtin_amdgcn_exp2f(-xh)) - 1.0f;
}
// tanh of unscaled cell state
__device__ __forceinline__ float thc(float c) {
    return 2.0f * __builtin_amdgcn_rcpf(1.0f + __builtin_amdgcn_exp2f(c * -TWOLOG2E)) - 1.0f;
}

// Single fused kernel. block = 256 thr = 4 waves; 16 batch rows/block (grid 1024,
// 4 blocks/CU). Wave l owns layer l; its 16 B-frags (128 gate-rows x K=64, bf16)
// are gathered from the fp32 weights ONCE into VGPRs (64 regs) -- zero weight
// traffic in the steady loop. Software pipeline over s: wave l computes t = s-l.
// h crosses layers via LDS in A-frag layout [row][unit] bf16 (stride 40 shorts),
// parity double-buffered by step; c-state in registers.
// Unit permutation: MFMA tile g, lane-col m computes gate T=g>>1 of unit 2m+(g&1),
// so the two h values per row pack into one u32 LDS write (2-way banks = free).
__global__ __launch_bounds__(256, 4)
void lstm_mfma(const float* __restrict__ xg,  const float* __restrict__ Wih0,
               const float* __restrict__ Wih, const float* __restrict__ Whh,
               const float* __restrict__ bih, const float* __restrict__ bhh,
               const float* __restrict__ Wlin,const float* __restrict__ blin,
               float* __restrict__ out) {
    __shared__ short        hb[4 * 2 * 640] __attribute__((aligned(16))); // [l][p][16 rows * 40]
    __shared__ unsigned int xb[64 * 16];                                  // [t][row] 2xbf16

    const int tid  = threadIdx.x;
    const int wv   = __builtin_amdgcn_readfirstlane(tid >> 6);  // layer id, uniform
    const int lane = tid & 63;
    const int m    = lane & 15;    // A-row / D-col index
    const int q    = lane >> 4;    // quad
    const int row0 = blockIdx.x * 16;

    // zero h buffers (both parities; first reads must see 0)
    for (int i = tid; i < 2560; i += 256) ((unsigned int*)hb)[i] = 0u;

    // stage x -> LDS bf16 [t][row] (coalesced: lanes sweep t)
    for (int i = tid; i < 1024; i += 256) {
        int r = i >> 6, t = i & 63;
        float x0 = xg[(size_t)(row0 + r) * 192 + t];
        float x1 = xg[(size_t)(row0 + r) * 192 + 64 + t];
        xb[t * 16 + r] = pk2(x0, x1);
    }

    // ---- one-time: gather this lane's B-frags + bias from fp32 weights ----
    // tile g, half c: lane (m,q) holds W_scaled[rowG][k = c*32 + q*8 .. +7]
    // rowG = T*32 + 2m + (g&1), T = g>>1; scale log2e (2log2e for T==2 tanh gate).
    // layer 0: k<2 = W_ih0 cols, k in [2,32) = 0, k>=32 = W_hh[0] (recurrent).
    bf16x8 bfr[8][2];
    float  bv[8];
#pragma unroll
    for (int g = 0; g < 8; ++g) {
        const int   T    = g >> 1;
        const int   rowG = T * 32 + 2 * m + (g & 1);
        const float sc   = (T == 2) ? TWOLOG2E : LOG2E;
        bv[g] = (bih[wv * 128 + rowG] + bhh[wv * 128 + rowG]) * sc;
#pragma unroll
        for (int c = 0; c < 2; ++c) {
            const int k0 = c * 32 + q * 8;
            float w[8];
            if (wv == 0) {
                if (c == 0) {
#pragma unroll
                    for (int jj = 0; jj < 8; ++jj) w[jj] = 0.0f;
                    if (q == 0) { w[0] = Wih0[rowG * 2]; w[1] = Wih0[rowG * 2 + 1]; }
                } else {
                    const float* src = Whh + rowG * 32 + (k0 - 32);
#pragma unroll
                    for (int jj = 0; jj < 8; ++jj) w[jj] = src[jj];
                }
            } else {
                const float* src = (c == 0) ? (Wih + (wv - 1) * 4096 + rowG * 32 + k0)
                                            : (Whh + wv * 4096 + rowG * 32 + (k0 - 32));
#pragma unroll
                for (int jj = 0; jj < 8; ++jj) w[jj] = src[jj];
            }
            bf16x8 fr;
#pragma unroll
            for (int jj = 0; jj < 8; ++jj) fr[jj] = (short)f2b(w[jj] * sc);
            bfr[g][c] = fr;
        }
    }

    float cst[2][4];
#pragma unroll
    for (int hf = 0; hf < 2; ++hf)
#pragma unroll
        for (int r = 0; r < 4; ++r) cst[hf][r] = 0.0f;

    __syncthreads();

    for (int s = 0; s < 67; ++s) {
        const int t = s - wv;                 // wave-uniform
        if (t >= 0 && t < 64) {
            const int rp = (s + 1) & 1;       // read parity ((s-1)&1)
            const int wp = s & 1;             // write parity
            const short* hrin  = hb + ((wv > 0 ? wv - 1 : 0) * 2 + rp) * 640;
            const short* hrrec = hb + (wv * 2 + rp) * 640;
            short*       hw    = hb + (wv * 2 + wp) * 640;

            bf16x8 a0, a1;
            if (wv == 0) {
                unsigned int xd = xb[t * 16 + m];
                unsigned int lo = (q == 0) ? xd : 0u;
                union { unsigned int u[4]; bf16x8 v; } au;
                au.u[0] = lo; au.u[1] = 0u; au.u[2] = 0u; au.u[3] = 0u;
                a0 = au.v;
            } else {
                a0 = *(const bf16x8*)(hrin + m * 40 + q * 8);
            }
            a1 = *(const bf16x8*)(hrrec + m * 40 + q * 8);

            float h0[4];   // half-0 h (unit 2m), held for the packed u32 write
#pragma unroll
            for (int hf = 0; hf < 2; ++hf) {
                f32x4 zz = {0.f, 0.f, 0.f, 0.f};
                f32x4 ai = __builtin_amdgcn_mfma_f32_16x16x32_bf16(a0, bfr[0 + hf][0], zz, 0, 0, 0);
                ai       = __builtin_amdgcn_mfma_f32_16x16x32_bf16(a1, bfr[0 + hf][1], ai, 0, 0, 0);
                f32x4 af = __builtin_amdgcn_mfma_f32_16x16x32_bf16(a0, bfr[2 + hf][0], zz, 0, 0, 0);
                af       = __builtin_amdgcn_mfma_f32_16x16x32_bf16(a1, bfr[2 + hf][1], af, 0, 0, 0);
                f32x4 ag = __builtin_amdgcn_mfma_f32_16x16x32_bf16(a0, bfr[4 + hf][0], zz, 0, 0, 0);
                ag       = __builtin_amdgcn_mfma_f32_16x16x32_bf16(a1, bfr[4 + hf][1], ag, 0, 0, 0);
                f32x4 ao = __builtin_amdgcn_mfma_f32_16x16x32_bf16(a0, bfr[6 + hf][0], zz, 0, 0, 0);
                ao       = __builtin_amdgcn_mfma_f32_16x16x32_bf16(a1, bfr[6 + hf][1], ao, 0, 0, 0);
#pragma unroll
                for (int r = 0; r < 4; ++r) {
                    float i_ = sig2(ai[r] + bv[0 + hf]);
                    float f_ = sig2(af[r] + bv[2 + hf]);
                    float g_ = th2 (ag[r] + bv[4 + hf]);
                    float o_ = sig2(ao[r] + bv[6 + hf]);
                    float cn = f_ * cst[hf][r] + i_ * g_;
                    cst[hf][r] = cn;
                    float hh = o_ * thc(cn);
                    if (hf == 0) {
                        h0[r] = hh;
                    } else {
                        // units 2m (h0) and 2m+1 (hh) -> one u32 write
                        ((unsigned int*)hw)[(q * 4 + r) * 20 + m] = pk2(h0[r], hh);
                    }
                }
            }
        }
        __syncthreads();
    }

    // output head: h[3][t=63] written at s=66 -> parity 0
    if (tid < 16) {
        const short* h3 = hb + (3 * 2 + 0) * 640;
        float s = blin[0];
#pragma unroll
        for (int k = 0; k < 32; ++k)
            s += Wlin[k] * b2f((unsigned short)h3[tid * 40 + k]);
        out[row0 + tid] = sig2(s * LOG2E);
    }
}

extern "C" void kernel_launch(void* const* d_in, const int* in_sizes, int n_in,
                              void* d_out, int out_size, void* d_ws, size_t ws_size,
                              hipStream_t stream) {
    const float* x    = (const float*)d_in[0];
    const float* Wih0 = (const float*)d_in[1];
    const float* Wih  = (const float*)d_in[2];
    const float* Whh  = (const float*)d_in[3];
    const float* bih  = (const float*)d_in[4];
    const float* bhh  = (const float*)d_in[5];
    const float* Wlin = (const float*)d_in[6];
    const float* blin = (const float*)d_in[7];
    float* out = (float*)d_out;

    lstm_mfma<<<1024, 256, 0, stream>>>(x, Wih0, Wih, Whh, bih, bhh, Wlin, blin, out);
}

// Round 8
// 232.674 us; speedup vs baseline: 1.1249x; 1.1249x over previous
//
#include <hip/hip_runtime.h>

typedef float  f32x4  __attribute__((ext_vector_type(4)));
typedef short  bf16x8 __attribute__((ext_vector_type(8)));

#define LOG2E      1.4426950408889634f
#define NLOG2E    -1.4426950408889634f
#define NTWOLOG2E -2.8853900817779268f

__device__ __forceinline__ unsigned short f2b(float f) {      // fp32 -> bf16 RNE
    unsigned int u = __builtin_bit_cast(unsigned int, f);
    u += 0x7fffu + ((u >> 16) & 1u);
    return (unsigned short)(u >> 16);
}
__device__ __forceinline__ float b2f(unsigned short s) {
    unsigned int u = ((unsigned int)s) << 16;
    return __builtin_bit_cast(float, u);
}
__device__ __forceinline__ unsigned int pk2(float lo, float hi) { // 2xbf16 pack
    return (unsigned int)f2b(lo) | ((unsigned int)f2b(hi) << 16);
}
__device__ __forceinline__ float frcp(float x) { return __builtin_amdgcn_rcpf(x); }
__device__ __forceinline__ float fex2(float x) { return __builtin_amdgcn_exp2f(x); }

// Single kernel. block = 256 thr = 4 waves, 32 batch rows (grid 512, 2 blocks/CU).
// Wave l owns layer l; 16 B-frags (128 gate-rows x K=64 bf16) gathered once into
// VGPRs, pre-scaled by -log2e (-2log2e for the g gate) so MFMA emits NEGATED
// scaled preacts; bias rides in the MFMA C operand (per-D-column = lane-uniform).
// 2-timestep super-steps: wave l computes t=2(S-l), t+1 per super-step -> 35
// barriers instead of 67. h crosses layers via LDS [l][parity][slot][row*40]
// bf16 A-frag layout; in-super-step recurrent read is own-wave (lgkm only).
// Epilogue uses shared-denominator activations:
//   i*g = (1-e_g)/[(1+e_i)(1+e_g)], f*c = c/(1+e_f), h = (1-e_c)/[(1+e_o)(1+e_c)]
// (e_* = exp2 of negated scaled preacts) -> 5 exp + 3 rcp per cell (was 5+5).
__global__ __launch_bounds__(256, 2)
void lstm_mfma(const float* __restrict__ xg,  const float* __restrict__ Wih0,
               const float* __restrict__ Wih, const float* __restrict__ Whh,
               const float* __restrict__ bih, const float* __restrict__ bhh,
               const float* __restrict__ Wlin,const float* __restrict__ blin,
               float* __restrict__ out) {
    __shared__ short        hb[16 * 1280] __attribute__((aligned(16))); // [l][p][slot][32row*40]
    __shared__ unsigned int xb[64 * 32];                                // [t][row] 2xbf16

    const int tid  = threadIdx.x;
    const int wv   = __builtin_amdgcn_readfirstlane(tid >> 6);  // layer id, uniform
    const int lane = tid & 63;
    const int m    = lane & 15;    // A-row / D-col index
    const int q    = lane >> 4;    // quad
    const int row0 = blockIdx.x * 32;

    // zero all h buffers (first reads must see 0)
    for (int i = tid; i < 10240; i += 256) ((unsigned int*)hb)[i] = 0u;

    // stage x -> LDS bf16 [t][row]
    for (int i = tid; i < 2048; i += 256) {
        int r = i >> 6, t = i & 63;
        float x0 = xg[(size_t)(row0 + r) * 192 + t];
        float x1 = xg[(size_t)(row0 + r) * 192 + 64 + t];
        xb[t * 32 + r] = pk2(x0, x1);
    }

    // ---- one-time gather of B-frags + bias (negated scales) ----
    // tile g: gate T=g>>1 of unit 2m+(g&1); rowG = T*32 + 2m + (g&1).
    bf16x8 bfr[8][2];
    float  bv[8];
#pragma unroll
    for (int g = 0; g < 8; ++g) {
        const int   T    = g >> 1;
        const int   rowG = T * 32 + 2 * m + (g & 1);
        const float sc   = (T == 2) ? NTWOLOG2E : NLOG2E;
        bv[g] = (bih[wv * 128 + rowG] + bhh[wv * 128 + rowG]) * sc;
#pragma unroll
        for (int c = 0; c < 2; ++c) {
            const int k0 = c * 32 + q * 8;
            float w[8];
            if (wv == 0) {
                if (c == 0) {
#pragma unroll
                    for (int jj = 0; jj < 8; ++jj) w[jj] = 0.0f;
                    if (q == 0) { w[0] = Wih0[rowG * 2]; w[1] = Wih0[rowG * 2 + 1]; }
                } else {
                    const float* src = Whh + rowG * 32 + (k0 - 32);
#pragma unroll
                    for (int jj = 0; jj < 8; ++jj) w[jj] = src[jj];
                }
            } else {
                const float* src = (c == 0) ? (Wih + (wv - 1) * 4096 + rowG * 32 + k0)
                                            : (Whh + wv * 4096 + rowG * 32 + (k0 - 32));
#pragma unroll
                for (int jj = 0; jj < 8; ++jj) w[jj] = src[jj];
            }
            bf16x8 fr;
#pragma unroll
            for (int jj = 0; jj < 8; ++jj) fr[jj] = (short)f2b(w[jj] * sc);
            bfr[g][c] = fr;
        }
    }

    float cst[2][2][4];   // [tt][hf][r]
#pragma unroll
    for (int tt = 0; tt < 2; ++tt)
#pragma unroll
        for (int hf = 0; hf < 2; ++hf)
#pragma unroll
            for (int r = 0; r < 4; ++r) cst[tt][hf][r] = 0.0f;

    __syncthreads();

    // one (t) cell-step for all 32 rows: reads pa0 (input frags; null => x path),
    // pa1 (recurrent frags), writes h to hwr.
    auto cell_step = [&](int t, const short* pa0, const short* pa1, short* hwr) {
#pragma unroll
        for (int tt = 0; tt < 2; ++tt) {
            bf16x8 a0, a1;
            if (wv == 0) {
                unsigned int xd = xb[t * 32 + tt * 16 + m];
                union { unsigned int u[4]; bf16x8 v; } au;
                au.u[0] = (q == 0) ? xd : 0u; au.u[1] = 0u; au.u[2] = 0u; au.u[3] = 0u;
                a0 = au.v;
            } else {
                a0 = *(const bf16x8*)(pa0 + (tt * 16 + m) * 40 + q * 8);
            }
            a1 = *(const bf16x8*)(pa1 + (tt * 16 + m) * 40 + q * 8);

            f32x4 acc[8];
#pragma unroll
            for (int g = 0; g < 8; ++g) {
                f32x4 cb = {bv[g], bv[g], bv[g], bv[g]};
                acc[g] = __builtin_amdgcn_mfma_f32_16x16x32_bf16(a0, bfr[g][0], cb, 0, 0, 0);
                acc[g] = __builtin_amdgcn_mfma_f32_16x16x32_bf16(a1, bfr[g][1], acc[g], 0, 0, 0);
            }
            float h0[4];
#pragma unroll
            for (int hf = 0; hf < 2; ++hf) {
#pragma unroll
                for (int r = 0; r < 4; ++r) {
                    float ei = fex2(acc[0 + hf][r]);          // e^{-a_i}
                    float ef = fex2(acc[2 + hf][r]);          // e^{-a_f}
                    float eg = fex2(acc[4 + hf][r]);          // e^{-2 a_g}
                    float eo = fex2(acc[6 + hf][r]);          // e^{-a_o}
                    float ig = (1.0f - eg) * frcp((1.0f + ei) * (1.0f + eg));
                    float fc = cst[tt][hf][r] * frcp(1.0f + ef);
                    float cn = ig + fc;
                    cst[tt][hf][r] = cn;
                    float ec = fex2(cn * NTWOLOG2E);          // e^{-2c}
                    float hh = (1.0f - ec) * frcp((1.0f + eo) * (1.0f + ec));
                    if (hf == 0) {
                        h0[r] = hh;
                    } else {
                        ((unsigned int*)hwr)[(tt * 16 + q * 4 + r) * 20 + m] = pk2(h0[r], hh);
                    }
                }
            }
        }
    };

    for (int S = 0; S < 35; ++S) {
        const int t0 = 2 * (S - wv);          // wave-uniform
        if (t0 >= 0 && t0 <= 62) {
            const int p  = S & 1;
            const int pb = p ^ 1;
            short*       Lc0 = hb + ((wv * 2 + p ) * 2    ) * 1280;  // own layer, cur parity, slot0
            short*       Lc1 = Lc0 + 1280;                            // slot1
            const short* Lp1 = hb + ((wv * 2 + pb) * 2 + 1) * 1280;  // own layer, prev parity, slot1
            const int    lb  = (wv > 0) ? (wv - 1) : 0;
            const short* Dp0 = hb + ((lb * 2 + pb) * 2    ) * 1280;  // layer below, prev parity, slot0
            const short* Dp1 = Dp0 + 1280;                            // slot1

            cell_step(t0,     Dp0, Lp1, Lc0);   // t0: input h_{l-1}(t0), recurrent h_l(t0-1)
            cell_step(t0 + 1, Dp1, Lc0, Lc1);   // t1: input h_{l-1}(t1), recurrent h_l(t0) (own write)
        }
        __syncthreads();
    }

    // output head: h3(t=63) -> S=34, p=0, slot1
    if (tid < 32) {
        const short* h3 = hb + ((3 * 2 + 0) * 2 + 1) * 1280;
        float s = blin[0];
#pragma unroll
        for (int k = 0; k < 32; ++k)
            s += Wlin[k] * b2f((unsigned short)h3[tid * 40 + k]);
        out[row0 + tid] = frcp(1.0f + fex2(s * NLOG2E));
    }
}

extern "C" void kernel_launch(void* const* d_in, const int* in_sizes, int n_in,
                              void* d_out, int out_size, void* d_ws, size_t ws_size,
                              hipStream_t stream) {
    const float* x    = (const float*)d_in[0];
    const float* Wih0 = (const float*)d_in[1];
    const float* Wih  = (const float*)d_in[2];
    const float* Whh  = (const float*)d_in[3];
    const float* bih  = (const float*)d_in[4];
    const float* bhh  = (const float*)d_in[5];
    const float* Wlin = (const float*)d_in[6];
    const float* blin = (const float*)d_in[7];
    float* out = (float*)d_out;

    lstm_mfma<<<512, 256, 0, stream>>>(x, Wih0, Wih, Whh, bih, bhh, Wlin, blin, out);
}

// Round 9
// 223.670 us; speedup vs baseline: 1.1702x; 1.0403x over previous
//
#include <hip/hip_runtime.h>

typedef float  f32x4  __attribute__((ext_vector_type(4)));
typedef short  bf16x8 __attribute__((ext_vector_type(8)));

#define LOG2E      1.4426950408889634f
#define NLOG2E    -1.4426950408889634f
#define NTWOLOG2E -2.8853900817779268f

__device__ __forceinline__ unsigned short f2b(float f) {      // fp32 -> bf16 RNE
    unsigned int u = __builtin_bit_cast(unsigned int, f);
    u += 0x7fffu + ((u >> 16) & 1u);
    return (unsigned short)(u >> 16);
}
__device__ __forceinline__ float b2f(unsigned short s) {
    unsigned int u = ((unsigned int)s) << 16;
    return __builtin_bit_cast(float, u);
}
// 2xbf16 RNE pack: HW v_cvt_pk_bf16_f32 when available, manual fallback
__device__ __forceinline__ unsigned int pk2(float lo, float hi) {
#if __has_builtin(__builtin_amdgcn_cvt_pk_bf16_f32)
    typedef __bf16 bf16x2 __attribute__((ext_vector_type(2)));
    bf16x2 p = __builtin_amdgcn_cvt_pk_bf16_f32(lo, hi);
    return __builtin_bit_cast(unsigned int, p);
#else
    return (unsigned int)f2b(lo) | ((unsigned int)f2b(hi) << 16);
#endif
}
__device__ __forceinline__ float frcp(float x) { return __builtin_amdgcn_rcpf(x); }
__device__ __forceinline__ float fex2(float x) { return __builtin_amdgcn_exp2f(x); }

// Single kernel. block = 256 thr = 4 waves, 32 batch rows (grid 512, 2 blocks/CU).
// Wave l owns layer l; 16 B-frags (128 gate-rows x K=64 bf16) live in VGPRs,
// pre-scaled by -log2e (-2log2e for g gate) -> MFMA emits NEGATED scaled preacts;
// bias rides in the MFMA C operand. 2-timestep super-steps (35 barriers).
// h crosses layers via LDS [l][parity][slot][32row*40] bf16 A-frag layout.
// Epilogue (per cell, 5 exp + 2 rcp):
//   p1=(1+ei)(1+eg); cn = [c*p1 + (1-eg)(1+ef)] * rcp(p1*(1+ef))
//   ec = exp2(-2c*log2e); h = (1-ec) * rcp((1+eo)(1+ec))
__global__ __launch_bounds__(256, 2)
void lstm_mfma(const float* __restrict__ xg,  const float* __restrict__ Wih0,
               const float* __restrict__ Wih, const float* __restrict__ Whh,
               const float* __restrict__ bih, const float* __restrict__ bhh,
               const float* __restrict__ Wlin,const float* __restrict__ blin,
               float* __restrict__ out) {
    __shared__ short        hb[16 * 1280] __attribute__((aligned(16))); // [l][p][slot][32row*40]
    __shared__ unsigned int xb[64 * 32];                                // [t][row] 2xbf16

    const int tid  = threadIdx.x;
    const int wv   = __builtin_amdgcn_readfirstlane(tid >> 6);  // layer id, uniform
    const int lane = tid & 63;
    const int m    = lane & 15;    // A-row / D-col index
    const int q    = lane >> 4;    // quad
    const int row0 = blockIdx.x * 32;

    // zero all h buffers (first reads must see 0)
    for (int i = tid; i < 10240; i += 256) ((unsigned int*)hb)[i] = 0u;

    // stage x -> LDS bf16 [t][row]
    for (int i = tid; i < 2048; i += 256) {
        int r = i >> 6, t = i & 63;
        float x0 = xg[(size_t)(row0 + r) * 192 + t];
        float x1 = xg[(size_t)(row0 + r) * 192 + 64 + t];
        xb[t * 32 + r] = pk2(x0, x1);
    }

    // ---- one-time gather of B-frags + bias (negated scales) ----
    // tile g: gate T=g>>1 of unit 2m+(g&1); rowG = T*32 + 2m + (g&1).
    bf16x8 bfr[8][2];
    float  bv[8];
#pragma unroll
    for (int g = 0; g < 8; ++g) {
        const int   T    = g >> 1;
        const int   rowG = T * 32 + 2 * m + (g & 1);
        const float sc   = (T == 2) ? NTWOLOG2E : NLOG2E;
        bv[g] = (bih[wv * 128 + rowG] + bhh[wv * 128 + rowG]) * sc;
#pragma unroll
        for (int c = 0; c < 2; ++c) {
            const int k0 = c * 32 + q * 8;
            float w[8];
            if (wv == 0) {
                if (c == 0) {
#pragma unroll
                    for (int jj = 0; jj < 8; ++jj) w[jj] = 0.0f;
                    if (q == 0) { w[0] = Wih0[rowG * 2]; w[1] = Wih0[rowG * 2 + 1]; }
                } else {
                    const float* src = Whh + rowG * 32 + (k0 - 32);
#pragma unroll
                    for (int jj = 0; jj < 8; ++jj) w[jj] = src[jj];
                }
            } else {
                const float* src = (c == 0) ? (Wih + (wv - 1) * 4096 + rowG * 32 + k0)
                                            : (Whh + wv * 4096 + rowG * 32 + (k0 - 32));
#pragma unroll
                for (int jj = 0; jj < 8; ++jj) w[jj] = src[jj];
            }
            bf16x8 fr;
#pragma unroll
            for (int jj = 0; jj < 8; ++jj) fr[jj] = (short)f2b(w[jj] * sc);
            bfr[g][c] = fr;
        }
    }

    float cst[2][2][4];   // [tt][hf][r]
#pragma unroll
    for (int tt = 0; tt < 2; ++tt)
#pragma unroll
        for (int hf = 0; hf < 2; ++hf)
#pragma unroll
            for (int r = 0; r < 4; ++r) cst[tt][hf][r] = 0.0f;

    __syncthreads();

    // one t cell-step for all 32 rows
    auto cell_step = [&](int t, const short* pa0, const short* pa1, short* hwr) {
        // prefetch all 4 A-frags before any MFMA (bury ds_read latency)
        bf16x8 a0[2], a1[2];
#pragma unroll
        for (int tt = 0; tt < 2; ++tt) {
            if (wv == 0) {
                unsigned int xd = xb[t * 32 + tt * 16 + m];
                union { unsigned int u[4]; bf16x8 v; } au;
                au.u[0] = (q == 0) ? xd : 0u; au.u[1] = 0u; au.u[2] = 0u; au.u[3] = 0u;
                a0[tt] = au.v;
            } else {
                a0[tt] = *(const bf16x8*)(pa0 + (tt * 16 + m) * 40 + q * 8);
            }
            a1[tt] = *(const bf16x8*)(pa1 + (tt * 16 + m) * 40 + q * 8);
        }
#pragma unroll
        for (int tt = 0; tt < 2; ++tt) {
            f32x4 acc[8];
#pragma unroll
            for (int g = 0; g < 8; ++g) {
                f32x4 cb = {bv[g], bv[g], bv[g], bv[g]};
                acc[g] = __builtin_amdgcn_mfma_f32_16x16x32_bf16(a0[tt], bfr[g][0], cb, 0, 0, 0);
                acc[g] = __builtin_amdgcn_mfma_f32_16x16x32_bf16(a1[tt], bfr[g][1], acc[g], 0, 0, 0);
            }
            float h0[4];
#pragma unroll
            for (int hf = 0; hf < 2; ++hf) {
#pragma unroll
                for (int r = 0; r < 4; ++r) {
                    float ei = fex2(acc[0 + hf][r]);          // e^{-a_i}
                    float ef = fex2(acc[2 + hf][r]);          // e^{-a_f}
                    float eg = fex2(acc[4 + hf][r]);          // e^{-2 a_g}
                    float eo = fex2(acc[6 + hf][r]);          // e^{-a_o}
                    float ap_f = 1.0f + ef;
                    float p1   = (1.0f + ei) * (1.0f + eg);
                    float R    = frcp(p1 * ap_f);
                    float t1   = (1.0f - eg) * ap_f;
                    float t2   = __builtin_fmaf(cst[tt][hf][r], p1, t1);
                    float cn   = t2 * R;
                    cst[tt][hf][r] = cn;
                    float ec = fex2(cn * NTWOLOG2E);          // e^{-2c}
                    float Rh = frcp((1.0f + eo) * (1.0f + ec));
                    float hh = (1.0f - ec) * Rh;
                    if (hf == 0) {
                        h0[r] = hh;
                    } else {
                        ((unsigned int*)hwr)[(tt * 16 + q * 4 + r) * 20 + m] = pk2(h0[r], hh);
                    }
                }
            }
        }
    };

    for (int S = 0; S < 35; ++S) {
        const int t0 = 2 * (S - wv);          // wave-uniform
        if (t0 >= 0 && t0 <= 62) {
            const int p  = S & 1;
            const int pb = p ^ 1;
            short*       Lc0 = hb + ((wv * 2 + p ) * 2    ) * 1280;  // own layer, cur parity, slot0
            short*       Lc1 = Lc0 + 1280;                            // slot1
            const short* Lp1 = hb + ((wv * 2 + pb) * 2 + 1) * 1280;  // own layer, prev parity, slot1
            const int    lb  = (wv > 0) ? (wv - 1) : 0;
            const short* Dp0 = hb + ((lb * 2 + pb) * 2    ) * 1280;  // layer below, prev parity, slot0
            const short* Dp1 = Dp0 + 1280;                            // slot1

            cell_step(t0,     Dp0, Lp1, Lc0);   // t0: input h_{l-1}(t0), recurrent h_l(t0-1)
            cell_step(t0 + 1, Dp1, Lc0, Lc1);   // t1: input h_{l-1}(t1), recurrent h_l(t0)
        }
        __syncthreads();
    }

    // output head: h3(t=63) -> S=34, p=0, slot1
    if (tid < 32) {
        const short* h3 = hb + ((3 * 2 + 0) * 2 + 1) * 1280;
        float s = blin[0];
#pragma unroll
        for (int k = 0; k < 32; ++k)
            s += Wlin[k] * b2f((unsigned short)h3[tid * 40 + k]);
        out[row0 + tid] = frcp(1.0f + fex2(s * NLOG2E));
    }
}

extern "C" void kernel_launch(void* const* d_in, const int* in_sizes, int n_in,
                              void* d_out, int out_size, void* d_ws, size_t ws_size,
                              hipStream_t stream) {
    const float* x    = (const float*)d_in[0];
    const float* Wih0 = (const float*)d_in[1];
    const float* Wih  = (const float*)d_in[2];
    const float* Whh  = (const float*)d_in[3];
    const float* bih  = (const float*)d_in[4];
    const float* bhh  = (const float*)d_in[5];
    const float* Wlin = (const float*)d_in[6];
    const float* blin = (const float*)d_in[7];
    float* out = (float*)d_out;

    lstm_mfma<<<512, 256, 0, stream>>>(x, Wih0, Wih, Whh, bih, bhh, Wlin, blin, out);
}